// Round 6
// baseline (262.234 us; speedup 1.0000x reference)
//
#include <hip/hip_runtime.h>

// VQ straight-through: B=32, V=4096, D=64, K=512. N = 131072 rows.
// Outputs (flat, concatenated): z_q_st [N,D] f32, z_q [N,D] f32, indices [N] (as f32).
//
// Correctness contract (established R2/R3, passing): replicate numpy fp32 bitwise —
//  - sums of squares: numpy pairwise_sum scalar 8-accumulator order, products
//    rounded separately (no FMA contraction into the sum)
//  - z@e.T dots: sequential single-accumulator FMA chain over d=0..63 (BLAS)
//  - d2 = fl(fl(A - 2*dot) + C); argmin: global first-min (min value, tie -> min k)
//
// R11: R10 (166us) showed VALU busy-time unchanged at ~126us vs the 54.6us
// FMA floor: ~10k non-FMA VALU instrs/wave. With z in LDS, the only candidate
// is the e-stream — it does NOT lower to scalar s_load (R5's SGPR=112 was the
// default alloc, not evidence); it's per-lane VMEM with per-lane 64-bit addr
// arithmetic, 64x redundant across lanes. Fix: e-tiles staged in LDS, read
// via broadcast ds_read_b128 (uniform addr, base+imm offsets => ZERO VALU per
// read, no bank conflicts). All 4 waves share a 64-code tile (16 KB staged
// coalesced); wave w computes codes [t*64+w*16, +16); 8 tiles, 2 barriers
// each. Inner group: 16 zc + 128 e-broadcast ds_reads + 512 FMA. Wave k-sets
// now interleave => cross-wave merge is lexicographic (value, index) == exact
// np.argmin first-min. Dots stay single-acc sequential d-ascending; LDS
// round-trips preserve bits; A/nrm/d2 untouched.

#define VQ_N (32 * 4096)
#define VQ_D 64
#define VQ_K 512

// Rounding barrier: forbids FMA contraction / reassociation through x.
__device__ __forceinline__ float freeze(float x) {
  asm volatile("" : "+v"(x));
  return x;
}

// ---- kernel 1: C_k = np.sum(emb*emb, -1) in numpy fp32 order ----
__global__ __launch_bounds__(256) void vq_norms_kernel(
    const float* __restrict__ emb, float* __restrict__ nrm) {
  int k = blockIdx.x * blockDim.x + threadIdx.x;
  if (k < VQ_K) {
    const float* e = emb + k * VQ_D;
    float r0 = freeze(e[0] * e[0]), r1 = freeze(e[1] * e[1]);
    float r2 = freeze(e[2] * e[2]), r3 = freeze(e[3] * e[3]);
    float r4 = freeze(e[4] * e[4]), r5 = freeze(e[5] * e[5]);
    float r6 = freeze(e[6] * e[6]), r7 = freeze(e[7] * e[7]);
#pragma unroll
    for (int i = 8; i < VQ_D; i += 8) {
      r0 += freeze(e[i + 0] * e[i + 0]); r1 += freeze(e[i + 1] * e[i + 1]);
      r2 += freeze(e[i + 2] * e[i + 2]); r3 += freeze(e[i + 3] * e[i + 3]);
      r4 += freeze(e[i + 4] * e[i + 4]); r5 += freeze(e[i + 5] * e[i + 5]);
      r6 += freeze(e[i + 6] * e[i + 6]); r7 += freeze(e[i + 7] * e[i + 7]);
    }
    nrm[k] = ((r0 + r1) + (r2 + r3)) + ((r4 + r5) + (r6 + r7));
  }
}

// ---- kernel 2: main — 64 rows/block; 64-code e-tiles shared by 4 waves ----
__global__ __launch_bounds__(256) void vq_main_kernel(
    const float* __restrict__ z_e, const float* __restrict__ emb,
    const float* __restrict__ nrm, float* __restrict__ out_st,
    float* __restrict__ out_q, float* __restrict__ out_idx) {
  __shared__ float4 z_lds[16][64];   // [d-chunk][row] : 16 KB z tile
  __shared__ float4 e_lds[64 * 16];  // 64-code e tile : 16 KB
  __shared__ float s_val[256];       // per (wave, row) partial best value
  __shared__ int s_idx[256];         // per (wave, row) partial best index
  __shared__ int s_best[64];         // final best index per row

  const int tid = threadIdx.x;
  const int lane = tid & 63;                                  // row in block
  const int wave = __builtin_amdgcn_readfirstlane(tid >> 6);  // wave-uniform
  const int row0 = blockIdx.x * 64;
  const int row = row0 + lane;

  // Stage z tile: 1024 float4s, coalesced (thread i -> row i>>4, chunk i&15).
  const float4* zg = (const float4*)(z_e + (size_t)row0 * VQ_D);
#pragma unroll
  for (int t = 0; t < 4; ++t) {
    int i = t * 256 + tid;
    z_lds[i & 15][i >> 4] = zg[i];
  }
  __syncthreads();

  // A = np.sum(z*z) in numpy 8-accumulator order (acc j gets d ≡ j mod 8);
  // chunk pair (2c, 2c+1) supplies d = 8c..8c+7. Products rounded separately.
  float r0, r1, r2, r3, r4, r5, r6, r7;
  {
    float4 p0 = z_lds[0][lane], p1 = z_lds[1][lane];
    r0 = freeze(p0.x * p0.x); r1 = freeze(p0.y * p0.y);
    r2 = freeze(p0.z * p0.z); r3 = freeze(p0.w * p0.w);
    r4 = freeze(p1.x * p1.x); r5 = freeze(p1.y * p1.y);
    r6 = freeze(p1.z * p1.z); r7 = freeze(p1.w * p1.w);
#pragma unroll
    for (int c = 2; c < 16; c += 2) {
      float4 q0 = z_lds[c][lane], q1 = z_lds[c + 1][lane];
      r0 += freeze(q0.x * q0.x); r1 += freeze(q0.y * q0.y);
      r2 += freeze(q0.z * q0.z); r3 += freeze(q0.w * q0.w);
      r4 += freeze(q1.x * q1.x); r5 += freeze(q1.y * q1.y);
      r6 += freeze(q1.z * q1.z); r7 += freeze(q1.w * q1.w);
    }
  }
  const float A = ((r0 + r1) + (r2 + r3)) + ((r4 + r5) + (r6 + r7));

  float bestv = 3.4e38f;
  int best = 0;

  // 8 tiles of 64 codes. Stage tile cooperatively (coalesced), then wave w
  // scans codes [t*64 + w*16, +16) in 2 groups of 8 via LDS broadcast reads.
  for (int t = 0; t < 8; ++t) {
    const float4* eg = (const float4*)emb + (size_t)t * 1024;
#pragma unroll
    for (int i = 0; i < 4; ++i) e_lds[i * 256 + tid] = eg[i * 256 + tid];
    __syncthreads();

#pragma unroll
    for (int g = 0; g < 2; ++g) {
      const int kl = wave * 16 + g * 8;  // local code base within tile
      const int kk = t * 64 + kl;        // global code base
      const float4* ep = &e_lds[kl * 16];
      float a0 = 0.f, a1 = 0.f, a2 = 0.f, a3 = 0.f;
      float a4 = 0.f, a5 = 0.f, a6 = 0.f, a7 = 0.f;
// Per code J: sequential single-accumulator FMA, d ascending (c asc, xyzw).
#define VQ_DOT4(ACC, J)                                                  \
  do {                                                                   \
    float4 f = ep[(J)*16 + c];                                           \
    ACC = fmaf(zc.x, f.x, ACC); ACC = fmaf(zc.y, f.y, ACC);              \
    ACC = fmaf(zc.z, f.z, ACC); ACC = fmaf(zc.w, f.w, ACC);              \
  } while (0)
#pragma unroll
      for (int c = 0; c < 16; ++c) {  // d = 4c..4c+3
        float4 zc = z_lds[c][lane];
        VQ_DOT4(a0, 0); VQ_DOT4(a1, 1); VQ_DOT4(a2, 2); VQ_DOT4(a3, 3);
        VQ_DOT4(a4, 4); VQ_DOT4(a5, 5); VQ_DOT4(a6, 6); VQ_DOT4(a7, 7);
      }
#undef VQ_DOT4
      // d2 = fl(fl(A - 2*dot) + C); 2*dot exact => fmaf(-2,a,A) == fl(A-2a).
      float t0 = fmaf(-2.0f, a0, A) + nrm[kk + 0];
      float t1 = fmaf(-2.0f, a1, A) + nrm[kk + 1];
      float t2 = fmaf(-2.0f, a2, A) + nrm[kk + 2];
      float t3 = fmaf(-2.0f, a3, A) + nrm[kk + 3];
      float t4 = fmaf(-2.0f, a4, A) + nrm[kk + 4];
      float t5 = fmaf(-2.0f, a5, A) + nrm[kk + 5];
      float t6 = fmaf(-2.0f, a6, A) + nrm[kk + 6];
      float t7 = fmaf(-2.0f, a7, A) + nrm[kk + 7];
      // Within-wave k is ascending (t, g, j all ascending) -> strict < keeps
      // the first minimum of this wave's subset.
      if (t0 < bestv) { bestv = t0; best = kk + 0; }
      if (t1 < bestv) { bestv = t1; best = kk + 1; }
      if (t2 < bestv) { bestv = t2; best = kk + 2; }
      if (t3 < bestv) { bestv = t3; best = kk + 3; }
      if (t4 < bestv) { bestv = t4; best = kk + 4; }
      if (t5 < bestv) { bestv = t5; best = kk + 5; }
      if (t6 < bestv) { bestv = t6; best = kk + 6; }
      if (t7 < bestv) { bestv = t7; best = kk + 7; }
    }
    __syncthreads();  // tile consumed; safe to overwrite e_lds
  }

  s_val[wave * 64 + lane] = bestv;
  s_idx[wave * 64 + lane] = best;
  __syncthreads();

  // Cross-wave argmin per row. Wave k-sets interleave, so merge
  // lexicographically: min value, tie -> min index == np.argmin first-min.
  if (tid < 64) {
    float v = s_val[tid];
    int b = s_idx[tid];
#pragma unroll
    for (int c = 1; c < 4; ++c) {
      float vc = s_val[c * 64 + tid];
      int bc = s_idx[c * 64 + tid];
      if (vc < v || (vc == v && bc < b)) { v = vc; b = bc; }
    }
    s_best[tid] = b;
    out_idx[row] = (float)b;
  }
  __syncthreads();

  // Coalesced output writes: 64 rows x 16 float4 per array.
  const float4* eg4 = (const float4*)emb;
  const size_t base4 = (size_t)blockIdx.x * 64 * 16;
  float4* o0 = (float4*)out_st;
  float4* o1 = (float4*)out_q;
#pragma unroll
  for (int t = 0; t < 4; ++t) {
    int i = t * 256 + tid;
    int r = i >> 4, j = i & 15;
    float4 v = eg4[s_best[r] * 16 + j];
    o0[base4 + i] = v;
    o1[base4 + i] = v;
  }
}

extern "C" void kernel_launch(void* const* d_in, const int* in_sizes, int n_in,
                              void* d_out, int out_size, void* d_ws,
                              size_t ws_size, hipStream_t stream) {
  const float* z_e = (const float*)d_in[0];  // [N, D] fp32
  const float* emb = (const float*)d_in[1];  // [K, D] fp32
  float* nrm = (float*)d_ws;                 // [K] fp32 scratch

  float* out_st = (float*)d_out;                 // [N, D]
  float* out_q = out_st + (size_t)VQ_N * VQ_D;   // [N, D]
  float* out_idx = out_q + (size_t)VQ_N * VQ_D;  // [N] as float

  vq_norms_kernel<<<(VQ_K + 255) / 256, 256, 0, stream>>>(emb, nrm);
  vq_main_kernel<<<VQ_N / 64, 256, 0, stream>>>(z_e, emb, nrm, out_st, out_q,
                                                out_idx);
}

// Round 8
// 239.166 us; speedup vs baseline: 1.0964x; 1.0964x over previous
//
#include <hip/hip_runtime.h>

// VQ straight-through: B=32, V=4096, D=64, K=512. N = 131072 rows.
// Outputs (flat, concatenated): z_q_st [N,D] f32, z_q [N,D] f32, indices [N] (as f32).
//
// Correctness contract (established R2/R3, passing): replicate numpy fp32 bitwise —
//  - sums of squares: numpy pairwise_sum scalar 8-accumulator order, products
//    rounded separately (no FMA contraction into the sum)
//  - z@e.T dots: sequential single-accumulator FMA chain over d=0..63 (BLAS)
//  - d2 = fl(fl(A - 2*dot) + C); argmin: global first-min (min value, tie -> min k)
//
// R13 = R12 with the crash fixed. R12's abort was an OOB output loop:
// 16 iters x 512 thr = 8192 float4 against a 4096-f4 block region, s_best
// indexed to 511 vs 256 entries -> wild global reads. Correct: 8 iters.
// The design is unchanged (untested-not-refuted): Mr=4 rows x Nr=16 codes
// per lane; per c-chunk 4 dense z + 16 broadcast e ds_reads feed 256 FMAs
// (per-FMA DS 0.195 -> 0.78 LDS-pipe util at 4 SIMDs — under the limit).
//  - 512-thread blocks (8 waves), 256 rows/block; lane owns rows lane+64m.
//  - z tile 64 KB + e tile 32 KB + A 1 KB + nrm 2 KB = 99 KB LDS (gfx950
//    allows up to 160 KB/WG; m201 example runs 128 KB). 1 block/CU.
//  - Waves split K interleaved: wave w owns codes {t*128 + 8j + w}; within-
//    wave k ascending over (t,j) -> strict < = first-min of wave's subset;
//    cross-wave merge lexicographic (value, index) == np.argmin first-min.
//  - Merge buffers alias the dead e-tile; s_best aliases dead A_lds.
// Numeric ops identical to R10/R11: A-phase is R10's verified code; dots are
// single-accumulator sequential d=0..63 (c outer, xyzw inner); d2 =
// fmaf(-2,a,A)+C. LDS round-trips preserve bits.

#define VQ_N (32 * 4096)
#define VQ_D 64
#define VQ_K 512
#define ROWS 256     // rows per block
#define THREADS 512  // 8 waves
#define TILE_K 128   // codes per staged e-tile
#define NT 4         // tiles = VQ_K / TILE_K
#define NR 16        // codes per wave per tile = TILE_K / 8 waves
#define MR 4         // rows per lane = ROWS / 64

// Rounding barrier: forbids FMA contraction / reassociation through x.
__device__ __forceinline__ float freeze(float x) {
  asm volatile("" : "+v"(x));
  return x;
}

// ---- kernel 1: C_k = np.sum(emb*emb, -1) in numpy fp32 order ----
__global__ __launch_bounds__(256) void vq_norms_kernel(
    const float* __restrict__ emb, float* __restrict__ nrm) {
  int k = blockIdx.x * blockDim.x + threadIdx.x;
  if (k < VQ_K) {
    const float* e = emb + k * VQ_D;
    float r0 = freeze(e[0] * e[0]), r1 = freeze(e[1] * e[1]);
    float r2 = freeze(e[2] * e[2]), r3 = freeze(e[3] * e[3]);
    float r4 = freeze(e[4] * e[4]), r5 = freeze(e[5] * e[5]);
    float r6 = freeze(e[6] * e[6]), r7 = freeze(e[7] * e[7]);
#pragma unroll
    for (int i = 8; i < VQ_D; i += 8) {
      r0 += freeze(e[i + 0] * e[i + 0]); r1 += freeze(e[i + 1] * e[i + 1]);
      r2 += freeze(e[i + 2] * e[i + 2]); r3 += freeze(e[i + 3] * e[i + 3]);
      r4 += freeze(e[i + 4] * e[i + 4]); r5 += freeze(e[i + 5] * e[i + 5]);
      r6 += freeze(e[i + 6] * e[i + 6]); r7 += freeze(e[i + 7] * e[i + 7]);
    }
    nrm[k] = ((r0 + r1) + (r2 + r3)) + ((r4 + r5) + (r6 + r7));
  }
}

// ---- kernel 2: main — 256 rows/block, 8 waves, Mr=4 x Nr=16 reg tile ----
__global__ __launch_bounds__(THREADS, 2) void vq_main_kernel(
    const float* __restrict__ z_e, const float* __restrict__ emb,
    const float* __restrict__ nrm, float* __restrict__ out_st,
    float* __restrict__ out_q, float* __restrict__ out_idx) {
  __shared__ float4 z_lds[16][ROWS];     // 64 KB [d-chunk][row]
  __shared__ float4 e_lds[TILE_K * 16];  // 32 KB [code][d-chunk]
  __shared__ float A_lds[ROWS];          // 1 KB
  __shared__ float nrm_lds[VQ_K];        // 2 KB

  const int tid = threadIdx.x;
  const int lane = tid & 63;
  const int w = __builtin_amdgcn_readfirstlane(tid >> 6);  // wave id 0..7
  const size_t row0 = (size_t)blockIdx.x * ROWS;

  // Stage z tile (4096 float4, 8/thread, coalesced) + nrm (1 float/thread).
  const float4* zg = (const float4*)(z_e + row0 * VQ_D);
#pragma unroll
  for (int t = 0; t < 8; ++t) {
    int i = t * THREADS + tid;
    z_lds[i & 15][i >> 4] = zg[i];
  }
  nrm_lds[tid] = nrm[tid];  // VQ_K == THREADS
  __syncthreads();

  // A-phase (R10's verified code, thread<->row): numpy 8-accumulator order,
  // acc j gets d ≡ j mod 8; chunk pair (2c,2c+1) supplies d = 8c..8c+7.
  if (tid < ROWS) {
    float4 p0 = z_lds[0][tid], p1 = z_lds[1][tid];
    float r0 = freeze(p0.x * p0.x), r1 = freeze(p0.y * p0.y);
    float r2 = freeze(p0.z * p0.z), r3 = freeze(p0.w * p0.w);
    float r4 = freeze(p1.x * p1.x), r5 = freeze(p1.y * p1.y);
    float r6 = freeze(p1.z * p1.z), r7 = freeze(p1.w * p1.w);
#pragma unroll
    for (int c = 2; c < 16; c += 2) {
      float4 q0 = z_lds[c][tid], q1 = z_lds[c + 1][tid];
      r0 += freeze(q0.x * q0.x); r1 += freeze(q0.y * q0.y);
      r2 += freeze(q0.z * q0.z); r3 += freeze(q0.w * q0.w);
      r4 += freeze(q1.x * q1.x); r5 += freeze(q1.y * q1.y);
      r6 += freeze(q1.z * q1.z); r7 += freeze(q1.w * q1.w);
    }
    A_lds[tid] = ((r0 + r1) + (r2 + r3)) + ((r4 + r5) + (r6 + r7));
  }
  __syncthreads();

  float Ar[MR];
#pragma unroll
  for (int m = 0; m < MR; ++m) Ar[m] = A_lds[lane + 64 * m];

  float bestv[MR];
  int besti[MR];
#pragma unroll
  for (int m = 0; m < MR; ++m) { bestv[m] = 3.4e38f; besti[m] = 0; }

  for (int t = 0; t < NT; ++t) {
    // Stage e tile: 2048 float4, 4/thread, coalesced, linear layout.
    const float4* eg = (const float4*)emb + (size_t)t * (TILE_K * 16);
#pragma unroll
    for (int i = 0; i < 4; ++i)
      e_lds[i * THREADS + tid] = eg[i * THREADS + tid];
    __syncthreads();

    float acc[MR][NR];
#pragma unroll
    for (int m = 0; m < MR; ++m)
#pragma unroll
      for (int j = 0; j < NR; ++j) acc[m][j] = 0.f;

#pragma unroll
    for (int c = 0; c < 16; ++c) {  // d = 4c..4c+3
      float4 zr[MR];
#pragma unroll
      for (int m = 0; m < MR; ++m) zr[m] = z_lds[c][lane + 64 * m];
#pragma unroll
      for (int j = 0; j < NR; ++j) {
        float4 f = e_lds[(8 * j + w) * 16 + c];  // uniform addr -> broadcast
#pragma unroll
        for (int m = 0; m < MR; ++m) {
          // Sequential single-accumulator chain, d ascending (BLAS order).
          acc[m][j] = fmaf(zr[m].x, f.x, acc[m][j]);
          acc[m][j] = fmaf(zr[m].y, f.y, acc[m][j]);
          acc[m][j] = fmaf(zr[m].z, f.z, acc[m][j]);
          acc[m][j] = fmaf(zr[m].w, f.w, acc[m][j]);
        }
      }
    }

    // d2 = fl(fl(A - 2*dot) + C); 2*dot exact => fmaf(-2,a,A) == fl(A-2a).
    // Within-wave k ascends over (t, j) -> strict < keeps wave-subset first-min.
#pragma unroll
    for (int j = 0; j < NR; ++j) {
      const int k = t * TILE_K + 8 * j + w;
      const float C = nrm_lds[k];
#pragma unroll
      for (int m = 0; m < MR; ++m) {
        float tv = fmaf(-2.0f, acc[m][j], Ar[m]) + C;
        if (tv < bestv[m]) { bestv[m] = tv; besti[m] = k; }
      }
    }
    __syncthreads();  // tile consumed; safe to overwrite e_lds
  }

  // Cross-wave merge. Buffers alias the dead e-tile (barrier above).
  float* sv = (float*)e_lds;                   // 8 KB: [wave][row]
  int* si = (int*)((float*)e_lds + 8 * ROWS);  // 8 KB: [wave][row]
#pragma unroll
  for (int m = 0; m < MR; ++m) {
    sv[w * ROWS + lane + 64 * m] = bestv[m];
    si[w * ROWS + lane + 64 * m] = besti[m];
  }
  __syncthreads();

  // Lexicographic (value, index) merge == np.argmin first-min (R11-verified).
  if (tid < ROWS) {
    float v = sv[tid];
    int b = si[tid];
#pragma unroll
    for (int q = 1; q < 8; ++q) {
      float vq = sv[q * ROWS + tid];
      int bq = si[q * ROWS + tid];
      if (vq < v || (vq == v && bq < b)) { v = vq; b = bq; }
    }
    ((int*)A_lds)[tid] = b;  // A_lds dead -> reuse as s_best
    out_idx[row0 + tid] = (float)b;
  }
  __syncthreads();

  // Coalesced output writes: 256 rows x 16 float4 per array = 4096 f4,
  // 512 threads -> 8 iterations (R12's bug was 16 -> OOB).
  const int* s_best = (const int*)A_lds;
  const float4* eg4 = (const float4*)emb;
  const size_t base4 = row0 * 16;
  float4* o0 = (float4*)out_st;
  float4* o1 = (float4*)out_q;
#pragma unroll
  for (int t = 0; t < 8; ++t) {
    int i = t * THREADS + tid;
    int r = i >> 4, j = i & 15;
    float4 v = eg4[s_best[r] * 16 + j];
    o0[base4 + i] = v;
    o1[base4 + i] = v;
  }
}

extern "C" void kernel_launch(void* const* d_in, const int* in_sizes, int n_in,
                              void* d_out, int out_size, void* d_ws,
                              size_t ws_size, hipStream_t stream) {
  const float* z_e = (const float*)d_in[0];  // [N, D] fp32
  const float* emb = (const float*)d_in[1];  // [K, D] fp32
  float* nrm = (float*)d_ws;                 // [K] fp32 scratch

  float* out_st = (float*)d_out;                 // [N, D]
  float* out_q = out_st + (size_t)VQ_N * VQ_D;   // [N, D]
  float* out_idx = out_q + (size_t)VQ_N * VQ_D;  // [N] as float

  vq_norms_kernel<<<(VQ_K + 255) / 256, 256, 0, stream>>>(emb, nrm);
  vq_main_kernel<<<VQ_N / ROWS, THREADS, 0, stream>>>(z_e, emb, nrm, out_st,
                                                      out_q, out_idx);
}